// Round 1
// 373.897 us; speedup vs baseline: 1.0137x; 1.0137x over previous
//
#include <hip/hip_runtime.h>
#include <hip/hip_bf16.h>
#include <hip/hip_fp16.h>
#include <float.h>
#include <stdint.h>

#define N_CAT   100000
#define N_USERS 50000
#define N_REL   32
#define D       64
#define NEDGE   1600000
#define NNZ     1000000

#define EB_SHIFT 9
#define EB_SIZE  512
#define NBKE     ((N_CAT + EB_SIZE - 1) / EB_SIZE)    // 196 edge buckets
#define UB_SHIFT 8
#define UB_SIZE  256
#define NBKU     ((N_USERS + UB_SIZE - 1) / UB_SIZE)  // 196 user buckets
#define NBK      (NBKE + NBKU)                        // 392

#define T1   4096      // pass1 tile (16 recs/thread @ 256 threads)
#define ECAP 15360     // pass2 edge bucket LDS capacity
#define UCAP 7680      // pass2 user bucket LDS capacity

// ---------------------------------------------------------------------------
// ws: norm2[N_CAT*32] f32 | ccnt[392] | cbase_e[197] | cbase_u[197] |
//     ccur_e[196] | ccur_u[196] | offs_e[100001] | offs_u[50001] |
//     sorted_ta[NEDGE] int | sorted_cv[NNZ] int2 | cat_f16[N_CAT*64] (aligned)
//     (~40.7 MB with f16 table; falls back to f32 gathers if ws too small)
// ---------------------------------------------------------------------------

__device__ __forceinline__ unsigned int pack_half2(float a, float b) {
    return (unsigned int)__half_as_ushort(__float2half_rn(a)) |
           ((unsigned int)__half_as_ushort(__float2half_rn(b)) << 16);
}

template<int F16>
__device__ __forceinline__ float cat_val(const float* __restrict__ cat,
                                         const __half* __restrict__ cath,
                                         size_t idx) {
    return F16 ? __half2float(cath[idx]) : cat[idx];
}

// norm2[n][r] = sum_d cat[n][d]^2 * W[r][d]^2.
// 4 threads/node (16 dims each), W^2 in 8 KB LDS, 32 accs/thread,
// quad-reduce via 2x shfl_xor, constant-index stores.
// W16: additionally emits cat_f16 (RTN) for the gather kernels.
template<int W16>
__global__ __launch_bounds__(256) void norm2_kernel(
        const float* __restrict__ cat,
        const float* __restrict__ W,
        float* __restrict__ norm2,
        unsigned short* __restrict__ cath) {
    __shared__ float4 w2[N_REL * 16];   // squared W, 8 KB
    int t = threadIdx.x;
    const float4* Wv = (const float4*)W;
    for (int i = t; i < N_REL * 16; i += 256) {
        float4 v = Wv[i];
        v.x *= v.x; v.y *= v.y; v.z *= v.z; v.w *= v.w;
        w2[i] = v;
    }
    __syncthreads();

    int node = blockIdx.x * 64 + (t >> 2);
    int q    = t & 3;                     // which 16-dim quarter
    if (node >= N_CAT) return;

    const float4* catv = (const float4*)cat;
    float acc[N_REL];
#pragma unroll
    for (int r = 0; r < N_REL; ++r) acc[r] = 0.f;

    uint2 hp[4];
#pragma unroll
    for (int c = 0; c < 4; ++c) {
        float4 xv = catv[(size_t)node * 16 + q * 4 + c];
        if (W16) {
            hp[c].x = pack_half2(xv.x, xv.y);
            hp[c].y = pack_half2(xv.z, xv.w);
        }
        xv.x *= xv.x; xv.y *= xv.y; xv.z *= xv.z; xv.w *= xv.w;
#pragma unroll
        for (int r = 0; r < N_REL; ++r) {
            float4 wv = w2[r * 16 + q * 4 + c];
            acc[r] += xv.x * wv.x + xv.y * wv.y + xv.z * wv.z + xv.w * wv.w;
        }
    }
    if (W16) {
        uint4* cv16 = (uint4*)cath;       // row = 64 halves = 8 x uint4
        cv16[(size_t)node * 8 + q * 2]     = make_uint4(hp[0].x, hp[0].y, hp[1].x, hp[1].y);
        cv16[(size_t)node * 8 + q * 2 + 1] = make_uint4(hp[2].x, hp[2].y, hp[3].x, hp[3].y);
    }
    // reduce across the 4 threads of this node (quad butterfly)
#pragma unroll
    for (int r = 0; r < N_REL; ++r) {
        acc[r] += __shfl_xor(acc[r], 1);
        acc[r] += __shfl_xor(acc[r], 2);
    }
    // each quarter-thread writes 8 rels (constant register indices per branch)
    float4* nv = (float4*)norm2;
    size_t base = (size_t)node * 8 + q * 2;
    if (q == 0) {
        nv[base]     = make_float4(acc[0],  acc[1],  acc[2],  acc[3]);
        nv[base + 1] = make_float4(acc[4],  acc[5],  acc[6],  acc[7]);
    } else if (q == 1) {
        nv[base]     = make_float4(acc[8],  acc[9],  acc[10], acc[11]);
        nv[base + 1] = make_float4(acc[12], acc[13], acc[14], acc[15]);
    } else if (q == 2) {
        nv[base]     = make_float4(acc[16], acc[17], acc[18], acc[19]);
        nv[base + 1] = make_float4(acc[20], acc[21], acc[22], acc[23]);
    } else {
        nv[base]     = make_float4(acc[24], acc[25], acc[26], acc[27]);
        nv[base + 1] = make_float4(acc[28], acc[29], acc[30], acc[31]);
    }
}

// per-WG LDS histogram over 392 coarse buckets, single flush
__global__ void coarse_hist_kernel(const int* __restrict__ head,
                                   const int* __restrict__ imr,
                                   int* __restrict__ ccnt) {
    __shared__ int h[NBK];
    int t = threadIdx.x;
    for (int i = t; i < NBK; i += 256) h[i] = 0;
    __syncthreads();
    int stride = gridDim.x * 256;
    for (int i = blockIdx.x * 256 + t; i < NEDGE + NNZ; i += stride) {
        if (i < NEDGE) atomicAdd(&h[head[i] >> EB_SHIFT], 1);
        else           atomicAdd(&h[NBKE + (imr[i - NEDGE] >> UB_SHIFT)], 1);
    }
    __syncthreads();
    for (int i = t; i < NBK; i += 256) if (h[i]) atomicAdd(&ccnt[i], h[i]);
}

// single-WG scan of 392 coarse bins -> bucket bases + cursors + sentinels
__global__ void coarse_scan_kernel(const int* __restrict__ ccnt,
                                   int* __restrict__ cbase_e, int* __restrict__ cbase_u,
                                   int* __restrict__ ccur_e,  int* __restrict__ ccur_u,
                                   int* __restrict__ offs_e,  int* __restrict__ offs_u) {
    __shared__ int sc[256];
    int t = threadIdx.x;
    int c = (t < NBKE) ? ccnt[t] : 0;
    sc[t] = c; __syncthreads();
    for (int off = 1; off < 256; off <<= 1) {
        int v = (t >= off) ? sc[t - off] : 0; __syncthreads();
        sc[t] += v; __syncthreads();
    }
    int excl = sc[t] - c;
    if (t < NBKE) { cbase_e[t] = excl; ccur_e[t] = excl; }
    if (t == NBKE - 1) cbase_e[NBKE] = excl + c;
    __syncthreads();
    c = (t < NBKU) ? ccnt[NBKE + t] : 0;
    sc[t] = c; __syncthreads();
    for (int off = 1; off < 256; off <<= 1) {
        int v = (t >= off) ? sc[t - off] : 0; __syncthreads();
        sc[t] += v; __syncthreads();
    }
    excl = sc[t] - c;
    if (t < NBKU) { cbase_u[t] = excl; ccur_u[t] = excl; }
    if (t == NBKU - 1) cbase_u[NBKU] = excl + c;
    if (t == 0) { offs_e[N_CAT] = NEDGE; offs_u[N_USERS] = NNZ; }
}

// pass1 edges: tile -> LDS count/scan -> ONE global atomic per (tile,bucket)
__global__ __launch_bounds__(256) void pass1_edges_kernel(
        const int* __restrict__ head, const int* __restrict__ tail,
        const int* __restrict__ etype, int* __restrict__ ccur_e,
        int* __restrict__ sorted_ta) {
    __shared__ int cnt[256], loc[256], base[256], sc[256];
    __shared__ int stage[T1];
    __shared__ int gpos[T1];
    int t = threadIdx.x;
    int tile = blockIdx.x * T1;
    cnt[t] = 0;
    __syncthreads();
    int rec[16], bk[16];
#pragma unroll
    for (int k = 0; k < 16; ++k) {
        int i = tile + k * 256 + t;
        if (i < NEDGE) {
            int h = head[i], tl = tail[i], r = etype[i] - 1;
            bk[k]  = h >> EB_SHIFT;
            rec[k] = ((h & (EB_SIZE - 1)) << 22) | (tl << 5) | r;
            atomicAdd(&cnt[bk[k]], 1);
        } else bk[k] = -1;
    }
    __syncthreads();
    int c = cnt[t];
    sc[t] = c; __syncthreads();
    for (int off = 1; off < 256; off <<= 1) {
        int v = (t >= off) ? sc[t - off] : 0; __syncthreads();
        sc[t] += v; __syncthreads();
    }
    loc[t] = sc[t] - c;
    if (t < NBKE && c > 0) base[t] = atomicAdd(&ccur_e[t], c);
    __syncthreads();
    cnt[t] = loc[t];
    __syncthreads();
#pragma unroll
    for (int k = 0; k < 16; ++k) {
        if (bk[k] >= 0) {
            int p = atomicAdd(&cnt[bk[k]], 1);
            stage[p] = rec[k];
            gpos[p]  = base[bk[k]] + (p - loc[bk[k]]);
        }
    }
    __syncthreads();
    int nv = min(T1, NEDGE - tile);
    for (int i = t; i < nv; i += 256) sorted_ta[gpos[i]] = stage[i];
}

__global__ __launch_bounds__(256) void pass1_users_kernel(
        const int* __restrict__ imr, const int* __restrict__ imc,
        const float* __restrict__ imv, int* __restrict__ ccur_u,
        int2* __restrict__ sorted_cv) {
    __shared__ int cnt[256], loc[256], base[256], sc[256];
    __shared__ int2 stage[T1];
    __shared__ int gpos[T1];
    int t = threadIdx.x;
    int tile = blockIdx.x * T1;
    cnt[t] = 0;
    __syncthreads();
    int2 rec[16]; int bk[16];
#pragma unroll
    for (int k = 0; k < 16; ++k) {
        int i = tile + k * 256 + t;
        if (i < NNZ) {
            int rr = imr[i];
            bk[k]  = rr >> UB_SHIFT;
            rec[k] = make_int2(((rr & (UB_SIZE - 1)) << 17) | imc[i],
                               __float_as_int(imv[i]));
            atomicAdd(&cnt[bk[k]], 1);
        } else bk[k] = -1;
    }
    __syncthreads();
    int c = cnt[t];
    sc[t] = c; __syncthreads();
    for (int off = 1; off < 256; off <<= 1) {
        int v = (t >= off) ? sc[t - off] : 0; __syncthreads();
        sc[t] += v; __syncthreads();
    }
    loc[t] = sc[t] - c;
    if (t < NBKU && c > 0) base[t] = atomicAdd(&ccur_u[t], c);
    __syncthreads();
    cnt[t] = loc[t];
    __syncthreads();
#pragma unroll
    for (int k = 0; k < 16; ++k) {
        if (bk[k] >= 0) {
            int p = atomicAdd(&cnt[bk[k]], 1);
            stage[p] = rec[k];
            gpos[p]  = base[bk[k]] + (p - loc[bk[k]]);
        }
    }
    __syncthreads();
    int nv = min(T1, NNZ - tile);
    for (int i = t; i < nv; i += 256) sorted_cv[gpos[i]] = stage[i];
}

// pass2: one WG per coarse bucket; fine counting-sort in LDS; writes fine offs
__global__ __launch_bounds__(256) void pass2_kernel(
        const int* __restrict__ cbase_e, const int* __restrict__ cbase_u,
        int* __restrict__ offs_e, int* __restrict__ offs_u,
        int* __restrict__ sorted_ta, int2* __restrict__ sorted_cv) {
    __shared__ int lds[UCAP * 2];        // 60 KB
    __shared__ int fh[EB_SIZE + 1];
    __shared__ int sc[256];
    int t = threadIdx.x;
    int b = blockIdx.x;
    if (b < NBKE) {
        int h0 = b << EB_SHIFT;
        int start = cbase_e[b], end = cbase_e[b + 1];
        int n = min(end - start, ECAP);
        for (int i = t; i < n; i += 256) lds[i] = sorted_ta[start + i];
        fh[2 * t] = 0; fh[2 * t + 1] = 0;
        __syncthreads();
        for (int i = t; i < n; i += 256) atomicAdd(&fh[lds[i] >> 22], 1);
        __syncthreads();
        int a = fh[2 * t], b2 = fh[2 * t + 1];
        sc[t] = a + b2; __syncthreads();
        for (int off = 1; off < 256; off <<= 1) {
            int v = (t >= off) ? sc[t - off] : 0; __syncthreads();
            sc[t] += v; __syncthreads();
        }
        int pe = sc[t] - (a + b2);
        int lim = min(EB_SIZE, N_CAT - h0);
        if (2 * t     < lim) offs_e[h0 + 2 * t]     = start + pe;
        if (2 * t + 1 < lim) offs_e[h0 + 2 * t + 1] = start + pe + a;
        fh[2 * t] = pe; fh[2 * t + 1] = pe + a;
        __syncthreads();
        for (int i = t; i < n; i += 256) {
            int rec = lds[i];
            int p = atomicAdd(&fh[rec >> 22], 1);
            sorted_ta[start + p] = rec & 0x3FFFFF;     // (tail<<5)|rel
        }
    } else {
        int k = b - NBKE;
        int u0 = k << UB_SHIFT;
        int start = cbase_u[k], end = cbase_u[k + 1];
        int n = min(end - start, UCAP);
        int2* lds2 = (int2*)lds;
        for (int i = t; i < n; i += 256) lds2[i] = sorted_cv[start + i];
        fh[t] = 0;
        __syncthreads();
        for (int i = t; i < n; i += 256) atomicAdd(&fh[lds2[i].x >> 17], 1);
        __syncthreads();
        int c = fh[t];
        sc[t] = c; __syncthreads();
        for (int off = 1; off < 256; off <<= 1) {
            int v = (t >= off) ? sc[t - off] : 0; __syncthreads();
            sc[t] += v; __syncthreads();
        }
        int excl = sc[t] - c;
        int lim = min(UB_SIZE, N_USERS - u0);
        if (t < lim) offs_u[u0 + t] = start + excl;
        fh[t] = excl;
        __syncthreads();
        for (int i = t; i < n; i += 256) {
            int2 rec = lds2[i];
            int p = atomicAdd(&fh[rec.x >> 17], 1);
            sorted_cv[start + p] = make_int2(rec.x & 0x1FFFF, rec.y);
        }
    }
}

// one wave per head; fast path deg<=64: single record read, softmax in registers.
// F16: aggregation gathers read the fp16 cat table (1 line/row instead of 2);
// att/softmax path stays fully f32 (norm2 f32) -- exp amplification forbids
// any quantization there. W staged in LDS (removes 1.6e6 per-edge L1 requests).
template<int F16>
__global__ void cat_agg_sorted_kernel(const int* __restrict__ offs_e,
                                      const int* __restrict__ sorted_ta,
                                      const float* __restrict__ norm2,
                                      const float* __restrict__ cat,
                                      const __half* __restrict__ cath,
                                      const float* __restrict__ W,
                                      float* __restrict__ cat_agg) {
    __shared__ float sW[N_REL * D];      // 8 KB
    for (int i = threadIdx.x; i < N_REL * D; i += 256) sW[i] = W[i];
    __syncthreads();

    int wv   = threadIdx.x >> 6;
    int lane = threadIdx.x & 63;
    int h = blockIdx.x * 4 + wv;
    int start = offs_e[h];
    int end   = offs_e[h + 1];
    int deg   = end - start;

    float a0 = 0.f, a1 = 0.f, a2 = 0.f, a3 = 0.f;

    if (deg <= 64) {
        int   rec = 0;
        float att = -FLT_MAX;
        if (lane < deg) {
            rec = sorted_ta[start + lane];
            int tt = rec >> 5, r = rec & 31;
            att = norm2[h * N_REL + r] * norm2[(size_t)tt * N_REL + r];
        }
        float m = att;
#pragma unroll
        for (int off = 32; off > 0; off >>= 1) m = fmaxf(m, __shfl_xor(m, off));
        float ex = (lane < deg) ? __expf(att - m) : 0.f;
        float ssum = ex;
#pragma unroll
        for (int off = 32; off > 0; off >>= 1) ssum += __shfl_xor(ssum, off);
        float w = (deg > 0) ? ex / ssum : 0.f;

        int j = 0;
        for (; j + 4 <= deg; j += 4) {
            int   tr0 = __shfl(rec, j + 0), tr1 = __shfl(rec, j + 1);
            int   tr2 = __shfl(rec, j + 2), tr3 = __shfl(rec, j + 3);
            float w0  = __shfl(w,   j + 0), w1  = __shfl(w,   j + 1);
            float w2  = __shfl(w,   j + 2), w3  = __shfl(w,   j + 3);
            a0 += w0 * cat_val<F16>(cat, cath, (size_t)(tr0 >> 5) * D + lane) * sW[(tr0 & 31) * D + lane];
            a1 += w1 * cat_val<F16>(cat, cath, (size_t)(tr1 >> 5) * D + lane) * sW[(tr1 & 31) * D + lane];
            a2 += w2 * cat_val<F16>(cat, cath, (size_t)(tr2 >> 5) * D + lane) * sW[(tr2 & 31) * D + lane];
            a3 += w3 * cat_val<F16>(cat, cath, (size_t)(tr3 >> 5) * D + lane) * sW[(tr3 & 31) * D + lane];
        }
        for (; j < deg; ++j) {
            int   tr = __shfl(rec, j);
            float ww = __shfl(w,   j);
            a0 += ww * cat_val<F16>(cat, cath, (size_t)(tr >> 5) * D + lane) * sW[(tr & 31) * D + lane];
        }
    } else {
        float m = -FLT_MAX;
        for (int j = lane; j < deg; j += 64) {
            int rec = sorted_ta[start + j];
            int tt = rec >> 5, r = rec & 31;
            m = fmaxf(m, norm2[h * N_REL + r] * norm2[(size_t)tt * N_REL + r]);
        }
#pragma unroll
        for (int off = 32; off > 0; off >>= 1) m = fmaxf(m, __shfl_xor(m, off));
        float ssum = 0.f;
        for (int j = lane; j < deg; j += 64) {
            int rec = sorted_ta[start + j];
            int tt = rec >> 5, r = rec & 31;
            ssum += __expf(norm2[h * N_REL + r] * norm2[(size_t)tt * N_REL + r] - m);
        }
#pragma unroll
        for (int off = 32; off > 0; off >>= 1) ssum += __shfl_xor(ssum, off);
        float inv = 1.f / ssum;
        for (int j0 = 0; j0 < deg; j0 += 64) {
            int n = min(64, deg - j0);
            int   rec = 0;
            float w   = 0.f;
            if (lane < n) {
                rec = sorted_ta[start + j0 + lane];
                int tt = rec >> 5, r = rec & 31;
                w = __expf(norm2[h * N_REL + r] * norm2[(size_t)tt * N_REL + r] - m) * inv;
            }
            for (int j = 0; j < n; ++j) {
                int   tr = __shfl(rec, j);
                float ww = __shfl(w,   j);
                a0 += ww * cat_val<F16>(cat, cath, (size_t)(tr >> 5) * D + lane) * sW[(tr & 31) * D + lane];
            }
        }
    }
    cat_agg[(size_t)h * D + lane] = (a0 + a1) + (a2 + a3);
}

template<int F16>
__global__ void spmm_user_kernel(const int* __restrict__ offs_u,
                                 const int2* __restrict__ sorted_cv,
                                 const float* __restrict__ cat,
                                 const __half* __restrict__ cath,
                                 const float* __restrict__ uemb,
                                 const float* __restrict__ W,
                                 float* __restrict__ uagg) {
    __shared__ float s_user[4][D];
    __shared__ float s_score[4][N_REL];
    int wv   = threadIdx.x >> 6;
    int lane = threadIdx.x & 63;
    int u = blockIdx.x * 4 + wv;
    int start = offs_u[u];
    int end   = offs_u[u + 1];
    int deg   = end - start;

    float a0 = 0.f, a1 = 0.f, a2 = 0.f, a3 = 0.f;
    for (int j0 = 0; j0 < deg; j0 += 64) {
        int n = min(64, deg - j0);
        int   my_c = 0;
        float my_v = 0.f;
        if (lane < n) {
            int2 cv = sorted_cv[start + j0 + lane];
            my_c = cv.x;
            my_v = __int_as_float(cv.y);
        }
        int j = 0;
        for (; j + 4 <= n; j += 4) {
            int   c0 = __shfl(my_c, j + 0), c1 = __shfl(my_c, j + 1);
            int   c2 = __shfl(my_c, j + 2), c3 = __shfl(my_c, j + 3);
            float v0 = __shfl(my_v, j + 0), v1 = __shfl(my_v, j + 1);
            float v2 = __shfl(my_v, j + 2), v3 = __shfl(my_v, j + 3);
            a0 += v0 * cat_val<F16>(cat, cath, (size_t)c0 * D + lane);
            a1 += v1 * cat_val<F16>(cat, cath, (size_t)c1 * D + lane);
            a2 += v2 * cat_val<F16>(cat, cath, (size_t)c2 * D + lane);
            a3 += v3 * cat_val<F16>(cat, cath, (size_t)c3 * D + lane);
        }
        for (; j < n; ++j) {
            int   cc = __shfl(my_c, j);
            float vv = __shfl(my_v, j);
            a0 += vv * cat_val<F16>(cat, cath, (size_t)cc * D + lane);
        }
    }
    float acc = (a0 + a1) + (a2 + a3);

    s_user[wv][lane] = uemb[(size_t)u * D + lane];
    __syncthreads();

    if (lane < N_REL) {
        float dot = 0.f;
#pragma unroll
        for (int d = 0; d < D; ++d) dot += s_user[wv][d] * W[lane * D + d];
        float mm = dot;
#pragma unroll
        for (int off = 16; off > 0; off >>= 1) mm = fmaxf(mm, __shfl_xor(mm, off));
        float ex = __expf(dot - mm);
        float sm = ex;
#pragma unroll
        for (int off = 16; off > 0; off >>= 1) sm += __shfl_xor(sm, off);
        s_score[wv][lane] = ex / sm;
    }
    __syncthreads();

    float proj = 0.f;
#pragma unroll
    for (int r = 0; r < N_REL; ++r) proj += s_score[wv][r] * W[r * D + lane];

    uagg[(size_t)u * D + lane] = acc * (1.f + proj);
}

extern "C" void kernel_launch(void* const* d_in, const int* in_sizes, int n_in,
                              void* d_out, int out_size, void* d_ws, size_t ws_size,
                              hipStream_t stream) {
    const float* cat   = (const float*)d_in[0];
    const float* uemb  = (const float*)d_in[1];
    const int*   eidx  = (const int*)d_in[2];
    const int*   etype = (const int*)d_in[3];
    const int*   imr   = (const int*)d_in[4];
    const int*   imc   = (const int*)d_in[5];
    const float* imv   = (const float*)d_in[6];
    const float* W     = (const float*)d_in[7];
    const int* head = eidx;
    const int* tail = eidx + NEDGE;

    float* out     = (float*)d_out;
    float* cat_agg = out;                         // [N_CAT, D]
    float* uagg    = out + (size_t)N_CAT * D;     // [N_USERS, D]

    float* norm2   = (float*)d_ws;
    int*   ccnt    = (int*)(norm2 + (size_t)N_CAT * N_REL);
    int*   cbase_e = ccnt + NBK;
    int*   cbase_u = cbase_e + NBKE + 1;
    int*   ccur_e  = cbase_u + NBKU + 1;
    int*   ccur_u  = ccur_e + NBKE;
    int*   offs_e  = ccur_u + NBKU;
    int*   offs_u  = offs_e + N_CAT + 1;
    int*   sorted_ta = offs_u + N_USERS + 1;
    int2*  sorted_cv = (int2*)(sorted_ta + NEDGE);

    // fp16 cat table (aligned 256 B for uint4 stores); runtime ws check with
    // f32 fallback so an under-sized workspace can't fault.
    unsigned short* cath_us =
        (unsigned short*)(((uintptr_t)(sorted_cv + NNZ) + 255) & ~(uintptr_t)255);
    size_t need = (size_t)((char*)(cath_us + (size_t)N_CAT * D) - (char*)d_ws);
    int use16 = (ws_size >= need);

    hipMemsetAsync(ccnt, 0, (size_t)NBK * sizeof(int), stream);

    coarse_hist_kernel<<<512, 256, 0, stream>>>(head, imr, ccnt);
    coarse_scan_kernel<<<1, 256, 0, stream>>>(ccnt, cbase_e, cbase_u,
                                              ccur_e, ccur_u, offs_e, offs_u);
    pass1_edges_kernel<<<(NEDGE + T1 - 1) / T1, 256, 0, stream>>>(
        head, tail, etype, ccur_e, sorted_ta);
    pass1_users_kernel<<<(NNZ + T1 - 1) / T1, 256, 0, stream>>>(
        imr, imc, imv, ccur_u, sorted_cv);
    pass2_kernel<<<NBK, 256, 0, stream>>>(cbase_e, cbase_u, offs_e, offs_u,
                                          sorted_ta, sorted_cv);
    if (use16) {
        norm2_kernel<1><<<(N_CAT + 63) / 64, 256, 0, stream>>>(cat, W, norm2, cath_us);
        cat_agg_sorted_kernel<1><<<N_CAT / 4, 256, 0, stream>>>(
            offs_e, sorted_ta, norm2, cat, (const __half*)cath_us, W, cat_agg);
        spmm_user_kernel<1><<<N_USERS / 4, 256, 0, stream>>>(
            offs_u, sorted_cv, cat, (const __half*)cath_us, uemb, W, uagg);
    } else {
        norm2_kernel<0><<<(N_CAT + 63) / 64, 256, 0, stream>>>(cat, W, norm2, nullptr);
        cat_agg_sorted_kernel<0><<<N_CAT / 4, 256, 0, stream>>>(
            offs_e, sorted_ta, norm2, cat, nullptr, W, cat_agg);
        spmm_user_kernel<0><<<N_USERS / 4, 256, 0, stream>>>(
            offs_u, sorted_cv, cat, nullptr, uemb, W, uagg);
    }
}

// Round 2
// 339.668 us; speedup vs baseline: 1.1159x; 1.1008x over previous
//
#include <hip/hip_runtime.h>
#include <hip/hip_bf16.h>
#include <hip/hip_fp16.h>
#include <float.h>
#include <stdint.h>

#define N_CAT   100000
#define N_USERS 50000
#define N_REL   32
#define D       64
#define NEDGE   1600000
#define NNZ     1000000

#define EB_SHIFT 9
#define EB_SIZE  512
#define NBKE     ((N_CAT + EB_SIZE - 1) / EB_SIZE)    // 196 edge buckets
#define UB_SHIFT 8
#define UB_SIZE  256
#define NBKU     ((N_USERS + UB_SIZE - 1) / UB_SIZE)  // 196 user buckets
#define NBK      (NBKE + NBKU)                        // 392

#define T1   4096      // pass1 tile (16 recs/thread @ 256 threads)
#define ECAP 15360     // pass2 edge bucket LDS capacity
#define UCAP 7680      // pass2 user bucket LDS capacity

// LDS W row stride in float4 (68 floats): breaks the "every 256B row starts at
// bank 0" 8-way conflict down to <=4-way for grouped ds_read_b128.
#define WSTRIDE 17

// ---------------------------------------------------------------------------
// ws: norm2[N_CAT*32] f32 | ccnt[392] | cbase_e[197] | cbase_u[197] |
//     ccur_e[196] | ccur_u[196] | offs_e[100001] | offs_u[50001] |
//     sorted_ta[NEDGE] int | sorted_cv[NNZ] int2 | cat_f16[N_CAT*64] (aligned)
// ---------------------------------------------------------------------------

__device__ __forceinline__ unsigned int pack_half2(float a, float b) {
    return (unsigned int)__half_as_ushort(__float2half_rn(a)) |
           ((unsigned int)__half_as_ushort(__float2half_rn(b)) << 16);
}

// Gather one 64-dim row, 8 lanes x 8 dims. F16: one uint4 = one 128B line.
template<int F16>
__device__ __forceinline__ void load_row8(const float4* __restrict__ catv4,
                                          const uint4* __restrict__ cath4,
                                          int row, int gl, float f[8]) {
    if (F16) {
        uint4 h = cath4[(size_t)row * 8 + gl];
        const __half2* hp = (const __half2*)&h;
        float2 a = __half22float2(hp[0]);
        float2 b = __half22float2(hp[1]);
        float2 c = __half22float2(hp[2]);
        float2 d = __half22float2(hp[3]);
        f[0] = a.x; f[1] = a.y; f[2] = b.x; f[3] = b.y;
        f[4] = c.x; f[5] = c.y; f[6] = d.x; f[7] = d.y;
    } else {
        float4 a = catv4[(size_t)row * 16 + gl * 2];
        float4 b = catv4[(size_t)row * 16 + gl * 2 + 1];
        f[0] = a.x; f[1] = a.y; f[2] = a.z; f[3] = a.w;
        f[4] = b.x; f[5] = b.y; f[6] = b.z; f[7] = b.w;
    }
}

// norm2[n][r] = sum_d cat[n][d]^2 * W[r][d]^2.  (unchanged from round 1)
template<int W16>
__global__ __launch_bounds__(256) void norm2_kernel(
        const float* __restrict__ cat,
        const float* __restrict__ W,
        float* __restrict__ norm2,
        unsigned short* __restrict__ cath) {
    __shared__ float4 w2[N_REL * 16];   // squared W, 8 KB
    int t = threadIdx.x;
    const float4* Wv = (const float4*)W;
    for (int i = t; i < N_REL * 16; i += 256) {
        float4 v = Wv[i];
        v.x *= v.x; v.y *= v.y; v.z *= v.z; v.w *= v.w;
        w2[i] = v;
    }
    __syncthreads();

    int node = blockIdx.x * 64 + (t >> 2);
    int q    = t & 3;
    if (node >= N_CAT) return;

    const float4* catv = (const float4*)cat;
    float acc[N_REL];
#pragma unroll
    for (int r = 0; r < N_REL; ++r) acc[r] = 0.f;

    uint2 hp[4];
#pragma unroll
    for (int c = 0; c < 4; ++c) {
        float4 xv = catv[(size_t)node * 16 + q * 4 + c];
        if (W16) {
            hp[c].x = pack_half2(xv.x, xv.y);
            hp[c].y = pack_half2(xv.z, xv.w);
        }
        xv.x *= xv.x; xv.y *= xv.y; xv.z *= xv.z; xv.w *= xv.w;
#pragma unroll
        for (int r = 0; r < N_REL; ++r) {
            float4 wv = w2[r * 16 + q * 4 + c];
            acc[r] += xv.x * wv.x + xv.y * wv.y + xv.z * wv.z + xv.w * wv.w;
        }
    }
    if (W16) {
        uint4* cv16 = (uint4*)cath;
        cv16[(size_t)node * 8 + q * 2]     = make_uint4(hp[0].x, hp[0].y, hp[1].x, hp[1].y);
        cv16[(size_t)node * 8 + q * 2 + 1] = make_uint4(hp[2].x, hp[2].y, hp[3].x, hp[3].y);
    }
#pragma unroll
    for (int r = 0; r < N_REL; ++r) {
        acc[r] += __shfl_xor(acc[r], 1);
        acc[r] += __shfl_xor(acc[r], 2);
    }
    float4* nv = (float4*)norm2;
    size_t base = (size_t)node * 8 + q * 2;
    if (q == 0) {
        nv[base]     = make_float4(acc[0],  acc[1],  acc[2],  acc[3]);
        nv[base + 1] = make_float4(acc[4],  acc[5],  acc[6],  acc[7]);
    } else if (q == 1) {
        nv[base]     = make_float4(acc[8],  acc[9],  acc[10], acc[11]);
        nv[base + 1] = make_float4(acc[12], acc[13], acc[14], acc[15]);
    } else if (q == 2) {
        nv[base]     = make_float4(acc[16], acc[17], acc[18], acc[19]);
        nv[base + 1] = make_float4(acc[20], acc[21], acc[22], acc[23]);
    } else {
        nv[base]     = make_float4(acc[24], acc[25], acc[26], acc[27]);
        nv[base + 1] = make_float4(acc[28], acc[29], acc[30], acc[31]);
    }
}

// per-WG LDS histogram over 392 coarse buckets, single flush
__global__ void coarse_hist_kernel(const int* __restrict__ head,
                                   const int* __restrict__ imr,
                                   int* __restrict__ ccnt) {
    __shared__ int h[NBK];
    int t = threadIdx.x;
    for (int i = t; i < NBK; i += 256) h[i] = 0;
    __syncthreads();
    int stride = gridDim.x * 256;
    for (int i = blockIdx.x * 256 + t; i < NEDGE + NNZ; i += stride) {
        if (i < NEDGE) atomicAdd(&h[head[i] >> EB_SHIFT], 1);
        else           atomicAdd(&h[NBKE + (imr[i - NEDGE] >> UB_SHIFT)], 1);
    }
    __syncthreads();
    for (int i = t; i < NBK; i += 256) if (h[i]) atomicAdd(&ccnt[i], h[i]);
}

// single-WG scan of 392 coarse bins -> bucket bases + cursors + sentinels
__global__ void coarse_scan_kernel(const int* __restrict__ ccnt,
                                   int* __restrict__ cbase_e, int* __restrict__ cbase_u,
                                   int* __restrict__ ccur_e,  int* __restrict__ ccur_u,
                                   int* __restrict__ offs_e,  int* __restrict__ offs_u) {
    __shared__ int sc[256];
    int t = threadIdx.x;
    int c = (t < NBKE) ? ccnt[t] : 0;
    sc[t] = c; __syncthreads();
    for (int off = 1; off < 256; off <<= 1) {
        int v = (t >= off) ? sc[t - off] : 0; __syncthreads();
        sc[t] += v; __syncthreads();
    }
    int excl = sc[t] - c;
    if (t < NBKE) { cbase_e[t] = excl; ccur_e[t] = excl; }
    if (t == NBKE - 1) cbase_e[NBKE] = excl + c;
    __syncthreads();
    c = (t < NBKU) ? ccnt[NBKE + t] : 0;
    sc[t] = c; __syncthreads();
    for (int off = 1; off < 256; off <<= 1) {
        int v = (t >= off) ? sc[t - off] : 0; __syncthreads();
        sc[t] += v; __syncthreads();
    }
    excl = sc[t] - c;
    if (t < NBKU) { cbase_u[t] = excl; ccur_u[t] = excl; }
    if (t == NBKU - 1) cbase_u[NBKU] = excl + c;
    if (t == 0) { offs_e[N_CAT] = NEDGE; offs_u[N_USERS] = NNZ; }
}

// pass1 edges: tile -> LDS count/scan -> ONE global atomic per (tile,bucket)
__global__ __launch_bounds__(256) void pass1_edges_kernel(
        const int* __restrict__ head, const int* __restrict__ tail,
        const int* __restrict__ etype, int* __restrict__ ccur_e,
        int* __restrict__ sorted_ta) {
    __shared__ int cnt[256], loc[256], base[256], sc[256];
    __shared__ int stage[T1];
    __shared__ int gpos[T1];
    int t = threadIdx.x;
    int tile = blockIdx.x * T1;
    cnt[t] = 0;
    __syncthreads();
    int rec[16], bk[16];
#pragma unroll
    for (int k = 0; k < 16; ++k) {
        int i = tile + k * 256 + t;
        if (i < NEDGE) {
            int h = head[i], tl = tail[i], r = etype[i] - 1;
            bk[k]  = h >> EB_SHIFT;
            rec[k] = ((h & (EB_SIZE - 1)) << 22) | (tl << 5) | r;
            atomicAdd(&cnt[bk[k]], 1);
        } else bk[k] = -1;
    }
    __syncthreads();
    int c = cnt[t];
    sc[t] = c; __syncthreads();
    for (int off = 1; off < 256; off <<= 1) {
        int v = (t >= off) ? sc[t - off] : 0; __syncthreads();
        sc[t] += v; __syncthreads();
    }
    loc[t] = sc[t] - c;
    if (t < NBKE && c > 0) base[t] = atomicAdd(&ccur_e[t], c);
    __syncthreads();
    cnt[t] = loc[t];
    __syncthreads();
#pragma unroll
    for (int k = 0; k < 16; ++k) {
        if (bk[k] >= 0) {
            int p = atomicAdd(&cnt[bk[k]], 1);
            stage[p] = rec[k];
            gpos[p]  = base[bk[k]] + (p - loc[bk[k]]);
        }
    }
    __syncthreads();
    int nv = min(T1, NEDGE - tile);
    for (int i = t; i < nv; i += 256) sorted_ta[gpos[i]] = stage[i];
}

__global__ __launch_bounds__(256) void pass1_users_kernel(
        const int* __restrict__ imr, const int* __restrict__ imc,
        const float* __restrict__ imv, int* __restrict__ ccur_u,
        int2* __restrict__ sorted_cv) {
    __shared__ int cnt[256], loc[256], base[256], sc[256];
    __shared__ int2 stage[T1];
    __shared__ int gpos[T1];
    int t = threadIdx.x;
    int tile = blockIdx.x * T1;
    cnt[t] = 0;
    __syncthreads();
    int2 rec[16]; int bk[16];
#pragma unroll
    for (int k = 0; k < 16; ++k) {
        int i = tile + k * 256 + t;
        if (i < NNZ) {
            int rr = imr[i];
            bk[k]  = rr >> UB_SHIFT;
            rec[k] = make_int2(((rr & (UB_SIZE - 1)) << 17) | imc[i],
                               __float_as_int(imv[i]));
            atomicAdd(&cnt[bk[k]], 1);
        } else bk[k] = -1;
    }
    __syncthreads();
    int c = cnt[t];
    sc[t] = c; __syncthreads();
    for (int off = 1; off < 256; off <<= 1) {
        int v = (t >= off) ? sc[t - off] : 0; __syncthreads();
        sc[t] += v; __syncthreads();
    }
    loc[t] = sc[t] - c;
    if (t < NBKU && c > 0) base[t] = atomicAdd(&ccur_u[t], c);
    __syncthreads();
    cnt[t] = loc[t];
    __syncthreads();
#pragma unroll
    for (int k = 0; k < 16; ++k) {
        if (bk[k] >= 0) {
            int p = atomicAdd(&cnt[bk[k]], 1);
            stage[p] = rec[k];
            gpos[p]  = base[bk[k]] + (p - loc[bk[k]]);
        }
    }
    __syncthreads();
    int nv = min(T1, NNZ - tile);
    for (int i = t; i < nv; i += 256) sorted_cv[gpos[i]] = stage[i];
}

// pass2: one WG per coarse bucket; fine counting-sort in LDS; writes fine offs
__global__ __launch_bounds__(256) void pass2_kernel(
        const int* __restrict__ cbase_e, const int* __restrict__ cbase_u,
        int* __restrict__ offs_e, int* __restrict__ offs_u,
        int* __restrict__ sorted_ta, int2* __restrict__ sorted_cv) {
    __shared__ int lds[UCAP * 2];        // 60 KB
    __shared__ int fh[EB_SIZE + 1];
    __shared__ int sc[256];
    int t = threadIdx.x;
    int b = blockIdx.x;
    if (b < NBKE) {
        int h0 = b << EB_SHIFT;
        int start = cbase_e[b], end = cbase_e[b + 1];
        int n = min(end - start, ECAP);
        for (int i = t; i < n; i += 256) lds[i] = sorted_ta[start + i];
        fh[2 * t] = 0; fh[2 * t + 1] = 0;
        __syncthreads();
        for (int i = t; i < n; i += 256) atomicAdd(&fh[lds[i] >> 22], 1);
        __syncthreads();
        int a = fh[2 * t], b2 = fh[2 * t + 1];
        sc[t] = a + b2; __syncthreads();
        for (int off = 1; off < 256; off <<= 1) {
            int v = (t >= off) ? sc[t - off] : 0; __syncthreads();
            sc[t] += v; __syncthreads();
        }
        int pe = sc[t] - (a + b2);
        int lim = min(EB_SIZE, N_CAT - h0);
        if (2 * t     < lim) offs_e[h0 + 2 * t]     = start + pe;
        if (2 * t + 1 < lim) offs_e[h0 + 2 * t + 1] = start + pe + a;
        fh[2 * t] = pe; fh[2 * t + 1] = pe + a;
        __syncthreads();
        for (int i = t; i < n; i += 256) {
            int rec = lds[i];
            int p = atomicAdd(&fh[rec >> 22], 1);
            sorted_ta[start + p] = rec & 0x3FFFFF;     // (tail<<5)|rel
        }
    } else {
        int k = b - NBKE;
        int u0 = k << UB_SHIFT;
        int start = cbase_u[k], end = cbase_u[k + 1];
        int n = min(end - start, UCAP);
        int2* lds2 = (int2*)lds;
        for (int i = t; i < n; i += 256) lds2[i] = sorted_cv[start + i];
        fh[t] = 0;
        __syncthreads();
        for (int i = t; i < n; i += 256) atomicAdd(&fh[lds2[i].x >> 17], 1);
        __syncthreads();
        int c = fh[t];
        sc[t] = c; __syncthreads();
        for (int off = 1; off < 256; off <<= 1) {
            int v = (t >= off) ? sc[t - off] : 0; __syncthreads();
            sc[t] += v; __syncthreads();
        }
        int excl = sc[t] - c;
        int lim = min(UB_SIZE, N_USERS - u0);
        if (t < lim) offs_u[u0 + t] = start + excl;
        fh[t] = excl;
        __syncthreads();
        for (int i = t; i < n; i += 256) {
            int2 rec = lds2[i];
            int p = atomicAdd(&fh[rec.x >> 17], 1);
            sorted_cv[start + p] = make_int2(rec.x & 0x1FFFF, rec.y);
        }
    }
}

// one wave per head. Softmax over edges (edge j lives in lane j) stays as
// before; the weighted gather is restructured into 8 groups x 8 lanes:
// each group gathers a DIFFERENT edge's cat row (8 lanes x uint4 = 1 line),
// so one load instruction = 8 scattered lines in flight, and the accA/accB
// unroll doubles that. Cross-group shfl_xor reduce once per node.
template<int F16>
__global__ __launch_bounds__(256) void cat_agg_sorted_kernel(
        const int* __restrict__ offs_e,
        const int* __restrict__ sorted_ta,
        const float* __restrict__ norm2,
        const float* __restrict__ cat,
        const uint4* __restrict__ cath4,
        const float* __restrict__ W,
        float* __restrict__ cat_agg) {
    __shared__ float4 sW4[N_REL * WSTRIDE];   // 8704 B, 68-float row stride
    {
        const float4* Wv = (const float4*)W;
        for (int i = threadIdx.x; i < N_REL * 16; i += 256)
            sW4[(i >> 4) * WSTRIDE + (i & 15)] = Wv[i];
    }
    __syncthreads();

    const float4* catv4 = (const float4*)cat;
    int wv   = threadIdx.x >> 6;
    int lane = threadIdx.x & 63;
    int grp  = lane >> 3;
    int gl   = lane & 7;
    int h = blockIdx.x * 4 + wv;
    int start = offs_e[h];
    int end   = offs_e[h + 1];
    int deg   = end - start;

    float accA[8], accB[8];
#pragma unroll
    for (int k = 0; k < 8; ++k) { accA[k] = 0.f; accB[k] = 0.f; }

    if (deg <= 64) {
        int   rec = 0;
        float att = -FLT_MAX;
        if (lane < deg) {
            rec = sorted_ta[start + lane];
            int tt = rec >> 5, r = rec & 31;
            att = norm2[h * N_REL + r] * norm2[(size_t)tt * N_REL + r];
        }
        float m = att;
#pragma unroll
        for (int off = 32; off > 0; off >>= 1) m = fmaxf(m, __shfl_xor(m, off));
        float ex = (lane < deg) ? __expf(att - m) : 0.f;
        float ssum = ex;
#pragma unroll
        for (int off = 32; off > 0; off >>= 1) ssum += __shfl_xor(ssum, off);
        float w = (deg > 0) ? ex / ssum : 0.f;

        for (int e = 0; e < deg; e += 16) {
            int   tA = __shfl(rec, e + grp);
            float wA = __shfl(w,   e + grp);
            int   tB = __shfl(rec, e + 8 + grp);
            float wB = __shfl(w,   e + 8 + grp);
            float fA[8], fB[8];
            load_row8<F16>(catv4, cath4, tA >> 5, gl, fA);
            load_row8<F16>(catv4, cath4, tB >> 5, gl, fB);
            const float4* wrA = &sW4[(tA & 31) * WSTRIDE + gl * 2];
            const float4* wrB = &sW4[(tB & 31) * WSTRIDE + gl * 2];
            float4 wa0 = wrA[0], wa1 = wrA[1];
            float4 wb0 = wrB[0], wb1 = wrB[1];
            accA[0] += wA * fA[0] * wa0.x;  accA[1] += wA * fA[1] * wa0.y;
            accA[2] += wA * fA[2] * wa0.z;  accA[3] += wA * fA[3] * wa0.w;
            accA[4] += wA * fA[4] * wa1.x;  accA[5] += wA * fA[5] * wa1.y;
            accA[6] += wA * fA[6] * wa1.z;  accA[7] += wA * fA[7] * wa1.w;
            accB[0] += wB * fB[0] * wb0.x;  accB[1] += wB * fB[1] * wb0.y;
            accB[2] += wB * fB[2] * wb0.z;  accB[3] += wB * fB[3] * wb0.w;
            accB[4] += wB * fB[4] * wb1.x;  accB[5] += wB * fB[5] * wb1.y;
            accB[6] += wB * fB[6] * wb1.z;  accB[7] += wB * fB[7] * wb1.w;
        }
    } else {
        float m = -FLT_MAX;
        for (int j = lane; j < deg; j += 64) {
            int rec = sorted_ta[start + j];
            int tt = rec >> 5, r = rec & 31;
            m = fmaxf(m, norm2[h * N_REL + r] * norm2[(size_t)tt * N_REL + r]);
        }
#pragma unroll
        for (int off = 32; off > 0; off >>= 1) m = fmaxf(m, __shfl_xor(m, off));
        float ssum = 0.f;
        for (int j = lane; j < deg; j += 64) {
            int rec = sorted_ta[start + j];
            int tt = rec >> 5, r = rec & 31;
            ssum += __expf(norm2[h * N_REL + r] * norm2[(size_t)tt * N_REL + r] - m);
        }
#pragma unroll
        for (int off = 32; off > 0; off >>= 1) ssum += __shfl_xor(ssum, off);
        float inv = 1.f / ssum;
        for (int j0 = 0; j0 < deg; j0 += 64) {
            int n = min(64, deg - j0);
            int   rec = 0;
            float w   = 0.f;
            if (lane < n) {
                rec = sorted_ta[start + j0 + lane];
                int tt = rec >> 5, r = rec & 31;
                w = __expf(norm2[h * N_REL + r] * norm2[(size_t)tt * N_REL + r] - m) * inv;
            }
            for (int e = 0; e < n; e += 16) {
                int   tA = __shfl(rec, e + grp);
                float wA = __shfl(w,   e + grp);
                int   tB = __shfl(rec, e + 8 + grp);
                float wB = __shfl(w,   e + 8 + grp);
                float fA[8], fB[8];
                load_row8<F16>(catv4, cath4, tA >> 5, gl, fA);
                load_row8<F16>(catv4, cath4, tB >> 5, gl, fB);
                const float4* wrA = &sW4[(tA & 31) * WSTRIDE + gl * 2];
                const float4* wrB = &sW4[(tB & 31) * WSTRIDE + gl * 2];
                float4 wa0 = wrA[0], wa1 = wrA[1];
                float4 wb0 = wrB[0], wb1 = wrB[1];
                accA[0] += wA * fA[0] * wa0.x;  accA[1] += wA * fA[1] * wa0.y;
                accA[2] += wA * fA[2] * wa0.z;  accA[3] += wA * fA[3] * wa0.w;
                accA[4] += wA * fA[4] * wa1.x;  accA[5] += wA * fA[5] * wa1.y;
                accA[6] += wA * fA[6] * wa1.z;  accA[7] += wA * fA[7] * wa1.w;
                accB[0] += wB * fB[0] * wb0.x;  accB[1] += wB * fB[1] * wb0.y;
                accB[2] += wB * fB[2] * wb0.z;  accB[3] += wB * fB[3] * wb0.w;
                accB[4] += wB * fB[4] * wb1.x;  accB[5] += wB * fB[5] * wb1.y;
                accB[6] += wB * fB[6] * wb1.z;  accB[7] += wB * fB[7] * wb1.w;
            }
        }
    }

    float o[8];
#pragma unroll
    for (int k = 0; k < 8; ++k) {
        float v = accA[k] + accB[k];
        v += __shfl_xor(v, 8);
        v += __shfl_xor(v, 16);
        v += __shfl_xor(v, 32);
        o[k] = v;
    }
    if (grp == 0) {
        float4* outv = (float4*)&cat_agg[(size_t)h * D];
        outv[gl * 2]     = make_float4(o[0], o[1], o[2], o[3]);
        outv[gl * 2 + 1] = make_float4(o[4], o[5], o[6], o[7]);
    }
}

// same 8x8 group restructure for the user spmm
template<int F16>
__global__ __launch_bounds__(256) void spmm_user_kernel(
        const int* __restrict__ offs_u,
        const int2* __restrict__ sorted_cv,
        const float* __restrict__ cat,
        const uint4* __restrict__ cath4,
        const float* __restrict__ uemb,
        const float* __restrict__ W,
        float* __restrict__ uagg) {
    __shared__ float4 sW4[N_REL * WSTRIDE];
    __shared__ float4 s_user4[4][16];
    __shared__ float  s_score[4][N_REL];
    {
        const float4* Wv = (const float4*)W;
        for (int i = threadIdx.x; i < N_REL * 16; i += 256)
            sW4[(i >> 4) * WSTRIDE + (i & 15)] = Wv[i];
    }
    __syncthreads();

    const float4* catv4 = (const float4*)cat;
    int wv   = threadIdx.x >> 6;
    int lane = threadIdx.x & 63;
    int grp  = lane >> 3;
    int gl   = lane & 7;
    int u = blockIdx.x * 4 + wv;
    int start = offs_u[u];
    int end   = offs_u[u + 1];
    int deg   = end - start;

    float accA[8], accB[8];
#pragma unroll
    for (int k = 0; k < 8; ++k) { accA[k] = 0.f; accB[k] = 0.f; }

    for (int j0 = 0; j0 < deg; j0 += 64) {
        int n = min(64, deg - j0);
        int   my_c = 0;
        float my_v = 0.f;
        if (lane < n) {
            int2 cv = sorted_cv[start + j0 + lane];
            my_c = cv.x;
            my_v = __int_as_float(cv.y);
        }
        for (int e = 0; e < n; e += 16) {
            int   cA = __shfl(my_c, e + grp);
            float vA = __shfl(my_v, e + grp);
            int   cB = __shfl(my_c, e + 8 + grp);
            float vB = __shfl(my_v, e + 8 + grp);
            float fA[8], fB[8];
            load_row8<F16>(catv4, cath4, cA, gl, fA);
            load_row8<F16>(catv4, cath4, cB, gl, fB);
#pragma unroll
            for (int k = 0; k < 8; ++k) {
                accA[k] += vA * fA[k];
                accB[k] += vB * fB[k];
            }
        }
    }

    float acc[8];
#pragma unroll
    for (int k = 0; k < 8; ++k) {
        float v = accA[k] + accB[k];
        v += __shfl_xor(v, 8);
        v += __shfl_xor(v, 16);
        v += __shfl_xor(v, 32);
        acc[k] = v;
    }

    // epilogue: score = softmax(u_emb @ W^T); out = acc * (1 + score @ W)
    ((float*)s_user4[wv])[lane] = uemb[(size_t)u * D + lane];
    __syncthreads();

    if (lane < N_REL) {
        float dot = 0.f;
        const float4* wr = &sW4[lane * WSTRIDE];
#pragma unroll
        for (int i = 0; i < 16; ++i) {
            float4 a = wr[i], b = s_user4[wv][i];
            dot += a.x * b.x + a.y * b.y + a.z * b.z + a.w * b.w;
        }
        float mm = dot;
#pragma unroll
        for (int off = 16; off > 0; off >>= 1) mm = fmaxf(mm, __shfl_xor(mm, off));
        float ex = __expf(dot - mm);
        float sm = ex;
#pragma unroll
        for (int off = 16; off > 0; off >>= 1) sm += __shfl_xor(sm, off);
        s_score[wv][lane] = ex / sm;
    }
    __syncthreads();

    float p[8];
#pragma unroll
    for (int k = 0; k < 8; ++k) p[k] = 0.f;
#pragma unroll
    for (int r = 0; r < N_REL; ++r) {
        float s = s_score[wv][r];
        float4 w0 = sW4[r * WSTRIDE + gl * 2];
        float4 w1 = sW4[r * WSTRIDE + gl * 2 + 1];
        p[0] += s * w0.x; p[1] += s * w0.y; p[2] += s * w0.z; p[3] += s * w0.w;
        p[4] += s * w1.x; p[5] += s * w1.y; p[6] += s * w1.z; p[7] += s * w1.w;
    }

    if (grp == 0) {
        float4* ov = (float4*)&uagg[(size_t)u * D];
        ov[gl * 2]     = make_float4(acc[0] * (1.f + p[0]), acc[1] * (1.f + p[1]),
                                     acc[2] * (1.f + p[2]), acc[3] * (1.f + p[3]));
        ov[gl * 2 + 1] = make_float4(acc[4] * (1.f + p[4]), acc[5] * (1.f + p[5]),
                                     acc[6] * (1.f + p[6]), acc[7] * (1.f + p[7]));
    }
}

extern "C" void kernel_launch(void* const* d_in, const int* in_sizes, int n_in,
                              void* d_out, int out_size, void* d_ws, size_t ws_size,
                              hipStream_t stream) {
    const float* cat   = (const float*)d_in[0];
    const float* uemb  = (const float*)d_in[1];
    const int*   eidx  = (const int*)d_in[2];
    const int*   etype = (const int*)d_in[3];
    const int*   imr   = (const int*)d_in[4];
    const int*   imc   = (const int*)d_in[5];
    const float* imv   = (const float*)d_in[6];
    const float* W     = (const float*)d_in[7];
    const int* head = eidx;
    const int* tail = eidx + NEDGE;

    float* out     = (float*)d_out;
    float* cat_agg = out;                         // [N_CAT, D]
    float* uagg    = out + (size_t)N_CAT * D;     // [N_USERS, D]

    float* norm2   = (float*)d_ws;
    int*   ccnt    = (int*)(norm2 + (size_t)N_CAT * N_REL);
    int*   cbase_e = ccnt + NBK;
    int*   cbase_u = cbase_e + NBKE + 1;
    int*   ccur_e  = cbase_u + NBKU + 1;
    int*   ccur_u  = ccur_e + NBKE;
    int*   offs_e  = ccur_u + NBKU;
    int*   offs_u  = offs_e + N_CAT + 1;
    int*   sorted_ta = offs_u + N_USERS + 1;
    int2*  sorted_cv = (int2*)(sorted_ta + NEDGE);

    unsigned short* cath_us =
        (unsigned short*)(((uintptr_t)(sorted_cv + NNZ) + 255) & ~(uintptr_t)255);
    size_t need = (size_t)((char*)(cath_us + (size_t)N_CAT * D) - (char*)d_ws);
    int use16 = (ws_size >= need);

    hipMemsetAsync(ccnt, 0, (size_t)NBK * sizeof(int), stream);

    coarse_hist_kernel<<<512, 256, 0, stream>>>(head, imr, ccnt);
    coarse_scan_kernel<<<1, 256, 0, stream>>>(ccnt, cbase_e, cbase_u,
                                              ccur_e, ccur_u, offs_e, offs_u);
    pass1_edges_kernel<<<(NEDGE + T1 - 1) / T1, 256, 0, stream>>>(
        head, tail, etype, ccur_e, sorted_ta);
    pass1_users_kernel<<<(NNZ + T1 - 1) / T1, 256, 0, stream>>>(
        imr, imc, imv, ccur_u, sorted_cv);
    pass2_kernel<<<NBK, 256, 0, stream>>>(cbase_e, cbase_u, offs_e, offs_u,
                                          sorted_ta, sorted_cv);
    if (use16) {
        norm2_kernel<1><<<(N_CAT + 63) / 64, 256, 0, stream>>>(cat, W, norm2, cath_us);
        cat_agg_sorted_kernel<1><<<N_CAT / 4, 256, 0, stream>>>(
            offs_e, sorted_ta, norm2, cat, (const uint4*)cath_us, W, cat_agg);
        spmm_user_kernel<1><<<N_USERS / 4, 256, 0, stream>>>(
            offs_u, sorted_cv, cat, (const uint4*)cath_us, uemb, W, uagg);
    } else {
        norm2_kernel<0><<<(N_CAT + 63) / 64, 256, 0, stream>>>(cat, W, norm2, nullptr);
        cat_agg_sorted_kernel<0><<<N_CAT / 4, 256, 0, stream>>>(
            offs_e, sorted_ta, norm2, cat, nullptr, W, cat_agg);
        spmm_user_kernel<0><<<N_USERS / 4, 256, 0, stream>>>(
            offs_u, sorted_cv, cat, nullptr, uemb, W, uagg);
    }
}

// Round 3
// 326.530 us; speedup vs baseline: 1.1608x; 1.0402x over previous
//
#include <hip/hip_runtime.h>
#include <hip/hip_bf16.h>
#include <hip/hip_fp16.h>
#include <float.h>
#include <stdint.h>

#define N_CAT   100000
#define N_USERS 50000
#define N_REL   32
#define D       64
#define NEDGE   1600000
#define NNZ     1000000

#define EB_SHIFT 9
#define EB_SIZE  512
#define NBKE     ((N_CAT + EB_SIZE - 1) / EB_SIZE)    // 196 edge buckets
#define UB_SHIFT 8
#define UB_SIZE  256
#define NBKU     ((N_USERS + UB_SIZE - 1) / UB_SIZE)  // 196 user buckets
#define NBK      (NBKE + NBKU)                        // 392

#define T1   4096      // pass1 tile (16 recs/thread @ 256 threads)
#define ECAP 15360     // pass2 edge bucket LDS capacity
#define UCAP 7680      // pass2 user bucket LDS capacity

// LDS W row stride in float4 (68 floats): breaks the "every 256B row starts at
// bank 0" 8-way conflict down to <=4-way for grouped ds_read_b128.
#define WSTRIDE 17

// ---------------------------------------------------------------------------
// ws: norm2[N_CAT*32] f32 | ccnt[392] | cbase_e[197] | cbase_u[197] |
//     ccur_e[196] | ccur_u[196] | offs_e[100001] | offs_u[50001] |
//     sorted_ta[NEDGE] int | sorted_cv[NNZ] int2 | cat_f16[N_CAT*64] (aligned)
// ---------------------------------------------------------------------------

__device__ __forceinline__ unsigned int pack_half2(float a, float b) {
    return (unsigned int)__half_as_ushort(__float2half_rn(a)) |
           ((unsigned int)__half_as_ushort(__float2half_rn(b)) << 16);
}

// Gather one 64-dim row, 8 lanes x 8 dims. F16: one uint4 = one 128B line.
template<int F16>
__device__ __forceinline__ void load_row8(const float4* __restrict__ catv4,
                                          const uint4* __restrict__ cath4,
                                          int row, int gl, float f[8]) {
    if (F16) {
        uint4 h = cath4[(size_t)row * 8 + gl];
        const __half2* hp = (const __half2*)&h;
        float2 a = __half22float2(hp[0]);
        float2 b = __half22float2(hp[1]);
        float2 c = __half22float2(hp[2]);
        float2 d = __half22float2(hp[3]);
        f[0] = a.x; f[1] = a.y; f[2] = b.x; f[3] = b.y;
        f[4] = c.x; f[5] = c.y; f[6] = d.x; f[7] = d.y;
    } else {
        float4 a = catv4[(size_t)row * 16 + gl * 2];
        float4 b = catv4[(size_t)row * 16 + gl * 2 + 1];
        f[0] = a.x; f[1] = a.y; f[2] = a.z; f[3] = a.w;
        f[4] = b.x; f[5] = b.y; f[6] = b.z; f[7] = b.w;
    }
}

// norm2[n][r] = sum_d cat[n][d]^2 * W[r][d]^2.
template<int W16>
__global__ __launch_bounds__(256) void norm2_kernel(
        const float* __restrict__ cat,
        const float* __restrict__ W,
        float* __restrict__ norm2,
        unsigned short* __restrict__ cath) {
    __shared__ float4 w2[N_REL * 16];   // squared W, 8 KB
    int t = threadIdx.x;
    const float4* Wv = (const float4*)W;
    for (int i = t; i < N_REL * 16; i += 256) {
        float4 v = Wv[i];
        v.x *= v.x; v.y *= v.y; v.z *= v.z; v.w *= v.w;
        w2[i] = v;
    }
    __syncthreads();

    int node = blockIdx.x * 64 + (t >> 2);
    int q    = t & 3;
    if (node >= N_CAT) return;

    const float4* catv = (const float4*)cat;
    float acc[N_REL];
#pragma unroll
    for (int r = 0; r < N_REL; ++r) acc[r] = 0.f;

    uint2 hp[4];
#pragma unroll
    for (int c = 0; c < 4; ++c) {
        float4 xv = catv[(size_t)node * 16 + q * 4 + c];
        if (W16) {
            hp[c].x = pack_half2(xv.x, xv.y);
            hp[c].y = pack_half2(xv.z, xv.w);
        }
        xv.x *= xv.x; xv.y *= xv.y; xv.z *= xv.z; xv.w *= xv.w;
#pragma unroll
        for (int r = 0; r < N_REL; ++r) {
            float4 wv = w2[r * 16 + q * 4 + c];
            acc[r] += xv.x * wv.x + xv.y * wv.y + xv.z * wv.z + xv.w * wv.w;
        }
    }
    if (W16) {
        uint4* cv16 = (uint4*)cath;
        cv16[(size_t)node * 8 + q * 2]     = make_uint4(hp[0].x, hp[0].y, hp[1].x, hp[1].y);
        cv16[(size_t)node * 8 + q * 2 + 1] = make_uint4(hp[2].x, hp[2].y, hp[3].x, hp[3].y);
    }
#pragma unroll
    for (int r = 0; r < N_REL; ++r) {
        acc[r] += __shfl_xor(acc[r], 1);
        acc[r] += __shfl_xor(acc[r], 2);
    }
    float4* nv = (float4*)norm2;
    size_t base = (size_t)node * 8 + q * 2;
    if (q == 0) {
        nv[base]     = make_float4(acc[0],  acc[1],  acc[2],  acc[3]);
        nv[base + 1] = make_float4(acc[4],  acc[5],  acc[6],  acc[7]);
    } else if (q == 1) {
        nv[base]     = make_float4(acc[8],  acc[9],  acc[10], acc[11]);
        nv[base + 1] = make_float4(acc[12], acc[13], acc[14], acc[15]);
    } else if (q == 2) {
        nv[base]     = make_float4(acc[16], acc[17], acc[18], acc[19]);
        nv[base + 1] = make_float4(acc[20], acc[21], acc[22], acc[23]);
    } else {
        nv[base]     = make_float4(acc[24], acc[25], acc[26], acc[27]);
        nv[base + 1] = make_float4(acc[28], acc[29], acc[30], acc[31]);
    }
}

// per-WG LDS histogram over 392 coarse buckets, single flush
__global__ void coarse_hist_kernel(const int* __restrict__ head,
                                   const int* __restrict__ imr,
                                   int* __restrict__ ccnt) {
    __shared__ int h[NBK];
    int t = threadIdx.x;
    for (int i = t; i < NBK; i += 256) h[i] = 0;
    __syncthreads();
    int stride = gridDim.x * 256;
    for (int i = blockIdx.x * 256 + t; i < NEDGE + NNZ; i += stride) {
        if (i < NEDGE) atomicAdd(&h[head[i] >> EB_SHIFT], 1);
        else           atomicAdd(&h[NBKE + (imr[i - NEDGE] >> UB_SHIFT)], 1);
    }
    __syncthreads();
    for (int i = t; i < NBK; i += 256) if (h[i]) atomicAdd(&ccnt[i], h[i]);
}

// single-WG scan of 392 coarse bins -> bucket bases + cursors + sentinels
__global__ void coarse_scan_kernel(const int* __restrict__ ccnt,
                                   int* __restrict__ cbase_e, int* __restrict__ cbase_u,
                                   int* __restrict__ ccur_e,  int* __restrict__ ccur_u,
                                   int* __restrict__ offs_e,  int* __restrict__ offs_u) {
    __shared__ int sc[256];
    int t = threadIdx.x;
    int c = (t < NBKE) ? ccnt[t] : 0;
    sc[t] = c; __syncthreads();
    for (int off = 1; off < 256; off <<= 1) {
        int v = (t >= off) ? sc[t - off] : 0; __syncthreads();
        sc[t] += v; __syncthreads();
    }
    int excl = sc[t] - c;
    if (t < NBKE) { cbase_e[t] = excl; ccur_e[t] = excl; }
    if (t == NBKE - 1) cbase_e[NBKE] = excl + c;
    __syncthreads();
    c = (t < NBKU) ? ccnt[NBKE + t] : 0;
    sc[t] = c; __syncthreads();
    for (int off = 1; off < 256; off <<= 1) {
        int v = (t >= off) ? sc[t - off] : 0; __syncthreads();
        sc[t] += v; __syncthreads();
    }
    excl = sc[t] - c;
    if (t < NBKU) { cbase_u[t] = excl; ccur_u[t] = excl; }
    if (t == NBKU - 1) cbase_u[NBKU] = excl + c;
    if (t == 0) { offs_e[N_CAT] = NEDGE; offs_u[N_USERS] = NNZ; }
}

// pass1 edges: tile -> LDS count/scan -> ONE global atomic per (tile,bucket)
__global__ __launch_bounds__(256) void pass1_edges_kernel(
        const int* __restrict__ head, const int* __restrict__ tail,
        const int* __restrict__ etype, int* __restrict__ ccur_e,
        int* __restrict__ sorted_ta) {
    __shared__ int cnt[256], loc[256], base[256], sc[256];
    __shared__ int stage[T1];
    __shared__ int gpos[T1];
    int t = threadIdx.x;
    int tile = blockIdx.x * T1;
    cnt[t] = 0;
    __syncthreads();
    int rec[16], bk[16];
#pragma unroll
    for (int k = 0; k < 16; ++k) {
        int i = tile + k * 256 + t;
        if (i < NEDGE) {
            int h = head[i], tl = tail[i], r = etype[i] - 1;
            bk[k]  = h >> EB_SHIFT;
            rec[k] = ((h & (EB_SIZE - 1)) << 22) | (tl << 5) | r;
            atomicAdd(&cnt[bk[k]], 1);
        } else bk[k] = -1;
    }
    __syncthreads();
    int c = cnt[t];
    sc[t] = c; __syncthreads();
    for (int off = 1; off < 256; off <<= 1) {
        int v = (t >= off) ? sc[t - off] : 0; __syncthreads();
        sc[t] += v; __syncthreads();
    }
    loc[t] = sc[t] - c;
    if (t < NBKE && c > 0) base[t] = atomicAdd(&ccur_e[t], c);
    __syncthreads();
    cnt[t] = loc[t];
    __syncthreads();
#pragma unroll
    for (int k = 0; k < 16; ++k) {
        if (bk[k] >= 0) {
            int p = atomicAdd(&cnt[bk[k]], 1);
            stage[p] = rec[k];
            gpos[p]  = base[bk[k]] + (p - loc[bk[k]]);
        }
    }
    __syncthreads();
    int nv = min(T1, NEDGE - tile);
    for (int i = t; i < nv; i += 256) sorted_ta[gpos[i]] = stage[i];
}

__global__ __launch_bounds__(256) void pass1_users_kernel(
        const int* __restrict__ imr, const int* __restrict__ imc,
        const float* __restrict__ imv, int* __restrict__ ccur_u,
        int2* __restrict__ sorted_cv) {
    __shared__ int cnt[256], loc[256], base[256], sc[256];
    __shared__ int2 stage[T1];
    __shared__ int gpos[T1];
    int t = threadIdx.x;
    int tile = blockIdx.x * T1;
    cnt[t] = 0;
    __syncthreads();
    int2 rec[16]; int bk[16];
#pragma unroll
    for (int k = 0; k < 16; ++k) {
        int i = tile + k * 256 + t;
        if (i < NNZ) {
            int rr = imr[i];
            bk[k]  = rr >> UB_SHIFT;
            rec[k] = make_int2(((rr & (UB_SIZE - 1)) << 17) | imc[i],
                               __float_as_int(imv[i]));
            atomicAdd(&cnt[bk[k]], 1);
        } else bk[k] = -1;
    }
    __syncthreads();
    int c = cnt[t];
    sc[t] = c; __syncthreads();
    for (int off = 1; off < 256; off <<= 1) {
        int v = (t >= off) ? sc[t - off] : 0; __syncthreads();
        sc[t] += v; __syncthreads();
    }
    loc[t] = sc[t] - c;
    if (t < NBKU && c > 0) base[t] = atomicAdd(&ccur_u[t], c);
    __syncthreads();
    cnt[t] = loc[t];
    __syncthreads();
#pragma unroll
    for (int k = 0; k < 16; ++k) {
        if (bk[k] >= 0) {
            int p = atomicAdd(&cnt[bk[k]], 1);
            stage[p] = rec[k];
            gpos[p]  = base[bk[k]] + (p - loc[bk[k]]);
        }
    }
    __syncthreads();
    int nv = min(T1, NNZ - tile);
    for (int i = t; i < nv; i += 256) sorted_cv[gpos[i]] = stage[i];
}

// pass2: one WG per coarse bucket; fine counting-sort in LDS; writes fine offs
__global__ __launch_bounds__(256) void pass2_kernel(
        const int* __restrict__ cbase_e, const int* __restrict__ cbase_u,
        int* __restrict__ offs_e, int* __restrict__ offs_u,
        int* __restrict__ sorted_ta, int2* __restrict__ sorted_cv) {
    __shared__ int lds[UCAP * 2];        // 60 KB
    __shared__ int fh[EB_SIZE + 1];
    __shared__ int sc[256];
    int t = threadIdx.x;
    int b = blockIdx.x;
    if (b < NBKE) {
        int h0 = b << EB_SHIFT;
        int start = cbase_e[b], end = cbase_e[b + 1];
        int n = min(end - start, ECAP);
        for (int i = t; i < n; i += 256) lds[i] = sorted_ta[start + i];
        fh[2 * t] = 0; fh[2 * t + 1] = 0;
        __syncthreads();
        for (int i = t; i < n; i += 256) atomicAdd(&fh[lds[i] >> 22], 1);
        __syncthreads();
        int a = fh[2 * t], b2 = fh[2 * t + 1];
        sc[t] = a + b2; __syncthreads();
        for (int off = 1; off < 256; off <<= 1) {
            int v = (t >= off) ? sc[t - off] : 0; __syncthreads();
            sc[t] += v; __syncthreads();
        }
        int pe = sc[t] - (a + b2);
        int lim = min(EB_SIZE, N_CAT - h0);
        if (2 * t     < lim) offs_e[h0 + 2 * t]     = start + pe;
        if (2 * t + 1 < lim) offs_e[h0 + 2 * t + 1] = start + pe + a;
        fh[2 * t] = pe; fh[2 * t + 1] = pe + a;
        __syncthreads();
        for (int i = t; i < n; i += 256) {
            int rec = lds[i];
            int p = atomicAdd(&fh[rec >> 22], 1);
            sorted_ta[start + p] = rec & 0x3FFFFF;     // (tail<<5)|rel
        }
    } else {
        int k = b - NBKE;
        int u0 = k << UB_SHIFT;
        int start = cbase_u[k], end = cbase_u[k + 1];
        int n = min(end - start, UCAP);
        int2* lds2 = (int2*)lds;
        for (int i = t; i < n; i += 256) lds2[i] = sorted_cv[start + i];
        fh[t] = 0;
        __syncthreads();
        for (int i = t; i < n; i += 256) atomicAdd(&fh[lds2[i].x >> 17], 1);
        __syncthreads();
        int c = fh[t];
        sc[t] = c; __syncthreads();
        for (int off = 1; off < 256; off <<= 1) {
            int v = (t >= off) ? sc[t - off] : 0; __syncthreads();
            sc[t] += v; __syncthreads();
        }
        int excl = sc[t] - c;
        int lim = min(UB_SIZE, N_USERS - u0);
        if (t < lim) offs_u[u0 + t] = start + excl;
        fh[t] = excl;
        __syncthreads();
        for (int i = t; i < n; i += 256) {
            int2 rec = lds2[i];
            int p = atomicAdd(&fh[rec.x >> 17], 1);
            sorted_cv[start + p] = make_int2(rec.x & 0x1FFFF, rec.y);
        }
    }
}

#define FMA8(ACC, WS, F, W0, W1)                                         \
    ACC[0] += WS * F[0] * W0.x;  ACC[1] += WS * F[1] * W0.y;             \
    ACC[2] += WS * F[2] * W0.z;  ACC[3] += WS * F[3] * W0.w;             \
    ACC[4] += WS * F[4] * W1.x;  ACC[5] += WS * F[5] * W1.y;             \
    ACC[6] += WS * F[6] * W1.z;  ACC[7] += WS * F[7] * W1.w;

// one wave per head. deg<=32 fast path (99.98% of heads at lambda=16):
// row gathers are issued BEFORE the softmax shfl chain (addresses depend only
// on rec, not on softmax), so the ~600cy gather latency hides under the
// ~400cy serial reduce. Reduce width shrinks to 16/32 lanes when possible.
// Lanes >= deg carry w=0 (exact), dead groups' w may be NaN but are never
// shfl-sourced.
template<int F16>
__global__ __launch_bounds__(256, 4) void cat_agg_sorted_kernel(
        const int* __restrict__ offs_e,
        const int* __restrict__ sorted_ta,
        const float* __restrict__ norm2,
        const float* __restrict__ cat,
        const uint4* __restrict__ cath4,
        const float* __restrict__ W,
        float* __restrict__ cat_agg) {
    __shared__ float4 sW4[N_REL * WSTRIDE];   // 8704 B, 68-float row stride
    {
        const float4* Wv = (const float4*)W;
        for (int i = threadIdx.x; i < N_REL * 16; i += 256)
            sW4[(i >> 4) * WSTRIDE + (i & 15)] = Wv[i];
    }
    __syncthreads();

    const float4* catv4 = (const float4*)cat;
    int wv   = threadIdx.x >> 6;
    int lane = threadIdx.x & 63;
    int grp  = lane >> 3;
    int gl   = lane & 7;
    int h = blockIdx.x * 4 + wv;
    int start = offs_e[h];
    int end   = offs_e[h + 1];
    int deg   = end - start;

    float accA[8], accB[8];
#pragma unroll
    for (int k = 0; k < 8; ++k) { accA[k] = 0.f; accB[k] = 0.f; }

    if (deg <= 32) {
        int rec = 0;
        if (lane < deg) rec = sorted_ta[start + lane];
        // issue att-input gathers (lanes >= deg read hot index 0, harmless)
        int tt = rec >> 5, r = rec & 31;
        float n2t = norm2[(size_t)tt * N_REL + r];
        float n2h = norm2[(size_t)h  * N_REL + r];

        // prefetch row data for both FMA blocks NOW (overlaps softmax chain)
        int tA0 = __shfl(rec, grp),      tB0 = __shfl(rec, 8 + grp);
        float fA0[8], fB0[8], fA1[8], fB1[8];
        load_row8<F16>(catv4, cath4, tA0 >> 5, gl, fA0);
        load_row8<F16>(catv4, cath4, tB0 >> 5, gl, fB0);
        int tA1 = 0, tB1 = 0;
        if (deg > 16) {
            tA1 = __shfl(rec, 16 + grp); tB1 = __shfl(rec, 24 + grp);
            load_row8<F16>(catv4, cath4, tA1 >> 5, gl, fA1);
            load_row8<F16>(catv4, cath4, tB1 >> 5, gl, fB1);
        }

        // softmax over live lanes only (4 levels if deg<=16, else 5)
        float att = (lane < deg) ? n2h * n2t : -FLT_MAX;
        float m = att;
        m = fmaxf(m, __shfl_xor(m, 1));
        m = fmaxf(m, __shfl_xor(m, 2));
        m = fmaxf(m, __shfl_xor(m, 4));
        m = fmaxf(m, __shfl_xor(m, 8));
        if (deg > 16) m = fmaxf(m, __shfl_xor(m, 16));
        float ex = (lane < deg) ? __expf(att - m) : 0.f;
        float ssum = ex;
        ssum += __shfl_xor(ssum, 1);
        ssum += __shfl_xor(ssum, 2);
        ssum += __shfl_xor(ssum, 4);
        ssum += __shfl_xor(ssum, 8);
        if (deg > 16) ssum += __shfl_xor(ssum, 16);
        float w = (deg > 0) ? ex / ssum : 0.f;

        float wA0 = __shfl(w, grp), wB0 = __shfl(w, 8 + grp);
        const float4* wrA0 = &sW4[(tA0 & 31) * WSTRIDE + gl * 2];
        const float4* wrB0 = &sW4[(tB0 & 31) * WSTRIDE + gl * 2];
        float4 wa00 = wrA0[0], wa01 = wrA0[1];
        float4 wb00 = wrB0[0], wb01 = wrB0[1];
        FMA8(accA, wA0, fA0, wa00, wa01)
        FMA8(accB, wB0, fB0, wb00, wb01)
        if (deg > 16) {
            float wA1 = __shfl(w, 16 + grp), wB1 = __shfl(w, 24 + grp);
            const float4* wrA1 = &sW4[(tA1 & 31) * WSTRIDE + gl * 2];
            const float4* wrB1 = &sW4[(tB1 & 31) * WSTRIDE + gl * 2];
            float4 wa10 = wrA1[0], wa11 = wrA1[1];
            float4 wb10 = wrB1[0], wb11 = wrB1[1];
            FMA8(accA, wA1, fA1, wa10, wa11)
            FMA8(accB, wB1, fB1, wb10, wb11)
        }
    } else if (deg <= 64) {
        int   rec = 0;
        float att = -FLT_MAX;
        if (lane < deg) {
            rec = sorted_ta[start + lane];
            int tt = rec >> 5, r = rec & 31;
            att = norm2[h * N_REL + r] * norm2[(size_t)tt * N_REL + r];
        }
        float m = att;
#pragma unroll
        for (int off = 32; off > 0; off >>= 1) m = fmaxf(m, __shfl_xor(m, off));
        float ex = (lane < deg) ? __expf(att - m) : 0.f;
        float ssum = ex;
#pragma unroll
        for (int off = 32; off > 0; off >>= 1) ssum += __shfl_xor(ssum, off);
        float w = (deg > 0) ? ex / ssum : 0.f;

        for (int e = 0; e < deg; e += 16) {
            int   tA = __shfl(rec, e + grp);
            float wA = __shfl(w,   e + grp);
            int   tB = __shfl(rec, e + 8 + grp);
            float wB = __shfl(w,   e + 8 + grp);
            float fA[8], fB[8];
            load_row8<F16>(catv4, cath4, tA >> 5, gl, fA);
            load_row8<F16>(catv4, cath4, tB >> 5, gl, fB);
            const float4* wrA = &sW4[(tA & 31) * WSTRIDE + gl * 2];
            const float4* wrB = &sW4[(tB & 31) * WSTRIDE + gl * 2];
            float4 wa0 = wrA[0], wa1 = wrA[1];
            float4 wb0 = wrB[0], wb1 = wrB[1];
            FMA8(accA, wA, fA, wa0, wa1)
            FMA8(accB, wB, fB, wb0, wb1)
        }
    } else {
        float m = -FLT_MAX;
        for (int j = lane; j < deg; j += 64) {
            int rec = sorted_ta[start + j];
            int tt = rec >> 5, r = rec & 31;
            m = fmaxf(m, norm2[h * N_REL + r] * norm2[(size_t)tt * N_REL + r]);
        }
#pragma unroll
        for (int off = 32; off > 0; off >>= 1) m = fmaxf(m, __shfl_xor(m, off));
        float ssum = 0.f;
        for (int j = lane; j < deg; j += 64) {
            int rec = sorted_ta[start + j];
            int tt = rec >> 5, r = rec & 31;
            ssum += __expf(norm2[h * N_REL + r] * norm2[(size_t)tt * N_REL + r] - m);
        }
#pragma unroll
        for (int off = 32; off > 0; off >>= 1) ssum += __shfl_xor(ssum, off);
        float inv = 1.f / ssum;
        for (int j0 = 0; j0 < deg; j0 += 64) {
            int n = min(64, deg - j0);
            int   rec = 0;
            float w   = 0.f;
            if (lane < n) {
                rec = sorted_ta[start + j0 + lane];
                int tt = rec >> 5, r = rec & 31;
                w = __expf(norm2[h * N_REL + r] * norm2[(size_t)tt * N_REL + r] - m) * inv;
            }
            for (int e = 0; e < n; e += 16) {
                int   tA = __shfl(rec, e + grp);
                float wA = __shfl(w,   e + grp);
                int   tB = __shfl(rec, e + 8 + grp);
                float wB = __shfl(w,   e + 8 + grp);
                float fA[8], fB[8];
                load_row8<F16>(catv4, cath4, tA >> 5, gl, fA);
                load_row8<F16>(catv4, cath4, tB >> 5, gl, fB);
                const float4* wrA = &sW4[(tA & 31) * WSTRIDE + gl * 2];
                const float4* wrB = &sW4[(tB & 31) * WSTRIDE + gl * 2];
                float4 wa0 = wrA[0], wa1 = wrA[1];
                float4 wb0 = wrB[0], wb1 = wrB[1];
                FMA8(accA, wA, fA, wa0, wa1)
                FMA8(accB, wB, fB, wb0, wb1)
            }
        }
    }

    float o[8];
#pragma unroll
    for (int k = 0; k < 8; ++k) {
        float v = accA[k] + accB[k];
        v += __shfl_xor(v, 8);
        v += __shfl_xor(v, 16);
        v += __shfl_xor(v, 32);
        o[k] = v;
    }
    if (grp == 0) {
        float4* outv = (float4*)&cat_agg[(size_t)h * D];
        outv[gl * 2]     = make_float4(o[0], o[1], o[2], o[3]);
        outv[gl * 2 + 1] = make_float4(o[4], o[5], o[6], o[7]);
    }
}

// spmm: same 8x8 group structure; deg<=32 fast path with full prefetch
template<int F16>
__global__ __launch_bounds__(256, 4) void spmm_user_kernel(
        const int* __restrict__ offs_u,
        const int2* __restrict__ sorted_cv,
        const float* __restrict__ cat,
        const uint4* __restrict__ cath4,
        const float* __restrict__ uemb,
        const float* __restrict__ W,
        float* __restrict__ uagg) {
    __shared__ float4 sW4[N_REL * WSTRIDE];
    __shared__ float4 s_user4[4][16];
    __shared__ float  s_score[4][N_REL];
    {
        const float4* Wv = (const float4*)W;
        for (int i = threadIdx.x; i < N_REL * 16; i += 256)
            sW4[(i >> 4) * WSTRIDE + (i & 15)] = Wv[i];
    }
    __syncthreads();

    const float4* catv4 = (const float4*)cat;
    int wv   = threadIdx.x >> 6;
    int lane = threadIdx.x & 63;
    int grp  = lane >> 3;
    int gl   = lane & 7;
    int u = blockIdx.x * 4 + wv;
    int start = offs_u[u];
    int end   = offs_u[u + 1];
    int deg   = end - start;

    float accA[8], accB[8];
#pragma unroll
    for (int k = 0; k < 8; ++k) { accA[k] = 0.f; accB[k] = 0.f; }

    if (deg <= 32) {
        int my_c = 0; float my_v = 0.f;
        if (lane < deg) {
            int2 cv = sorted_cv[start + lane];
            my_c = cv.x;
            my_v = __int_as_float(cv.y);
        }
        int   cA0 = __shfl(my_c, grp),     cB0 = __shfl(my_c, 8 + grp);
        float vA0 = __shfl(my_v, grp),     vB0 = __shfl(my_v, 8 + grp);
        float fA0[8], fB0[8], fA1[8], fB1[8];
        load_row8<F16>(catv4, cath4, cA0, gl, fA0);
        load_row8<F16>(catv4, cath4, cB0, gl, fB0);
        float vA1 = 0.f, vB1 = 0.f;
        if (deg > 16) {
            int cA1 = __shfl(my_c, 16 + grp), cB1 = __shfl(my_c, 24 + grp);
            vA1 = __shfl(my_v, 16 + grp); vB1 = __shfl(my_v, 24 + grp);
            load_row8<F16>(catv4, cath4, cA1, gl, fA1);
            load_row8<F16>(catv4, cath4, cB1, gl, fB1);
#pragma unroll
            for (int k = 0; k < 8; ++k) {
                accA[k] += vA1 * fA1[k];
                accB[k] += vB1 * fB1[k];
            }
        }
#pragma unroll
        for (int k = 0; k < 8; ++k) {
            accA[k] += vA0 * fA0[k];
            accB[k] += vB0 * fB0[k];
        }
    } else {
        for (int j0 = 0; j0 < deg; j0 += 64) {
            int n = min(64, deg - j0);
            int   my_c = 0;
            float my_v = 0.f;
            if (lane < n) {
                int2 cv = sorted_cv[start + j0 + lane];
                my_c = cv.x;
                my_v = __int_as_float(cv.y);
            }
            for (int e = 0; e < n; e += 16) {
                int   cA = __shfl(my_c, e + grp);
                float vA = __shfl(my_v, e + grp);
                int   cB = __shfl(my_c, e + 8 + grp);
                float vB = __shfl(my_v, e + 8 + grp);
                float fA[8], fB[8];
                load_row8<F16>(catv4, cath4, cA, gl, fA);
                load_row8<F16>(catv4, cath4, cB, gl, fB);
#pragma unroll
                for (int k = 0; k < 8; ++k) {
                    accA[k] += vA * fA[k];
                    accB[k] += vB * fB[k];
                }
            }
        }
    }

    float acc[8];
#pragma unroll
    for (int k = 0; k < 8; ++k) {
        float v = accA[k] + accB[k];
        v += __shfl_xor(v, 8);
        v += __shfl_xor(v, 16);
        v += __shfl_xor(v, 32);
        acc[k] = v;
    }

    // epilogue: score = softmax(u_emb @ W^T); out = acc * (1 + score @ W)
    ((float*)s_user4[wv])[lane] = uemb[(size_t)u * D + lane];
    __syncthreads();

    if (lane < N_REL) {
        float dot = 0.f;
        const float4* wr = &sW4[lane * WSTRIDE];
#pragma unroll
        for (int i = 0; i < 16; ++i) {
            float4 a = wr[i], b = s_user4[wv][i];
            dot += a.x * b.x + a.y * b.y + a.z * b.z + a.w * b.w;
        }
        float mm = dot;
#pragma unroll
        for (int off = 16; off > 0; off >>= 1) mm = fmaxf(mm, __shfl_xor(mm, off));
        float ex = __expf(dot - mm);
        float sm = ex;
#pragma unroll
        for (int off = 16; off > 0; off >>= 1) sm += __shfl_xor(sm, off);
        s_score[wv][lane] = ex / sm;
    }
    __syncthreads();

    float p[8];
#pragma unroll
    for (int k = 0; k < 8; ++k) p[k] = 0.f;
#pragma unroll
    for (int r = 0; r < N_REL; ++r) {
        float s = s_score[wv][r];
        float4 w0 = sW4[r * WSTRIDE + gl * 2];
        float4 w1 = sW4[r * WSTRIDE + gl * 2 + 1];
        p[0] += s * w0.x; p[1] += s * w0.y; p[2] += s * w0.z; p[3] += s * w0.w;
        p[4] += s * w1.x; p[5] += s * w1.y; p[6] += s * w1.z; p[7] += s * w1.w;
    }

    if (grp == 0) {
        float4* ov = (float4*)&uagg[(size_t)u * D];
        ov[gl * 2]     = make_float4(acc[0] * (1.f + p[0]), acc[1] * (1.f + p[1]),
                                     acc[2] * (1.f + p[2]), acc[3] * (1.f + p[3]));
        ov[gl * 2 + 1] = make_float4(acc[4] * (1.f + p[4]), acc[5] * (1.f + p[5]),
                                     acc[6] * (1.f + p[6]), acc[7] * (1.f + p[7]));
    }
}

extern "C" void kernel_launch(void* const* d_in, const int* in_sizes, int n_in,
                              void* d_out, int out_size, void* d_ws, size_t ws_size,
                              hipStream_t stream) {
    const float* cat   = (const float*)d_in[0];
    const float* uemb  = (const float*)d_in[1];
    const int*   eidx  = (const int*)d_in[2];
    const int*   etype = (const int*)d_in[3];
    const int*   imr   = (const int*)d_in[4];
    const int*   imc   = (const int*)d_in[5];
    const float* imv   = (const float*)d_in[6];
    const float* W     = (const float*)d_in[7];
    const int* head = eidx;
    const int* tail = eidx + NEDGE;

    float* out     = (float*)d_out;
    float* cat_agg = out;                         // [N_CAT, D]
    float* uagg    = out + (size_t)N_CAT * D;     // [N_USERS, D]

    float* norm2   = (float*)d_ws;
    int*   ccnt    = (int*)(norm2 + (size_t)N_CAT * N_REL);
    int*   cbase_e = ccnt + NBK;
    int*   cbase_u = cbase_e + NBKE + 1;
    int*   ccur_e  = cbase_u + NBKU + 1;
    int*   ccur_u  = ccur_e + NBKE;
    int*   offs_e  = ccur_u + NBKU;
    int*   offs_u  = offs_e + N_CAT + 1;
    int*   sorted_ta = offs_u + N_USERS + 1;
    int2*  sorted_cv = (int2*)(sorted_ta + NEDGE);

    unsigned short* cath_us =
        (unsigned short*)(((uintptr_t)(sorted_cv + NNZ) + 255) & ~(uintptr_t)255);
    size_t need = (size_t)((char*)(cath_us + (size_t)N_CAT * D) - (char*)d_ws);
    int use16 = (ws_size >= need);

    hipMemsetAsync(ccnt, 0, (size_t)NBK * sizeof(int), stream);

    coarse_hist_kernel<<<512, 256, 0, stream>>>(head, imr, ccnt);
    coarse_scan_kernel<<<1, 256, 0, stream>>>(ccnt, cbase_e, cbase_u,
                                              ccur_e, ccur_u, offs_e, offs_u);
    pass1_edges_kernel<<<(NEDGE + T1 - 1) / T1, 256, 0, stream>>>(
        head, tail, etype, ccur_e, sorted_ta);
    pass1_users_kernel<<<(NNZ + T1 - 1) / T1, 256, 0, stream>>>(
        imr, imc, imv, ccur_u, sorted_cv);
    pass2_kernel<<<NBK, 256, 0, stream>>>(cbase_e, cbase_u, offs_e, offs_u,
                                          sorted_ta, sorted_cv);
    if (use16) {
        norm2_kernel<1><<<(N_CAT + 63) / 64, 256, 0, stream>>>(cat, W, norm2, cath_us);
        cat_agg_sorted_kernel<1><<<N_CAT / 4, 256, 0, stream>>>(
            offs_e, sorted_ta, norm2, cat, (const uint4*)cath_us, W, cat_agg);
        spmm_user_kernel<1><<<N_USERS / 4, 256, 0, stream>>>(
            offs_u, sorted_cv, cat, (const uint4*)cath_us, uemb, W, uagg);
    } else {
        norm2_kernel<0><<<(N_CAT + 63) / 64, 256, 0, stream>>>(cat, W, norm2, nullptr);
        cat_agg_sorted_kernel<0><<<N_CAT / 4, 256, 0, stream>>>(
            offs_e, sorted_ta, norm2, cat, nullptr, W, cat_agg);
        spmm_user_kernel<0><<<N_USERS / 4, 256, 0, stream>>>(
            offs_u, sorted_cv, cat, nullptr, uemb, W, uagg);
    }
}